// Round 7
// baseline (350.839 us; speedup 1.0000x reference)
//
#include <hip/hip_runtime.h>

typedef unsigned short ushort_t;
typedef __bf16 bf16x8 __attribute__((ext_vector_type(8)));
typedef float floatx4 __attribute__((ext_vector_type(4)));

#define B_ 8
#define N_ 8192
#define S_ 2048
#define D1_ 128
#define D2_ 256
#define INCH_ 384
#define M_ 65536  // B*N

// ---------- workspace layout (bytes) ----------
constexpr size_t OFF_STATS = 0;          // 6144 B used
constexpr size_t OFF_W0B   = 8192;       // 256*384*2 = 196608
constexpr size_t OFF_W1B   = 204800;     // 128*256*2 = 65536
constexpr size_t OFF_X2P   = 270336;     // 8*2048*16 = 262144 (float4 x,y,z,0.5*|x|^2)
constexpr size_t OFF_P2T   = 532480;     // 8*2048*256*2 = 8388608 bf16
constexpr size_t OFF_XC    = 8921088;    // 65536*384*2 = 50331648 bf16 ; Y2b overlays after GEMM1
constexpr size_t OFF_Y1    = 59252736;   // 65536*256*2 = 33554432 bf16

__device__ __forceinline__ ushort_t f2bf(float f) {
  unsigned int u = __float_as_uint(f);
  unsigned int r = u + 0x7fffu + ((u >> 16) & 1u);
  return (ushort_t)(r >> 16);
}
__device__ __forceinline__ float bf2f(ushort_t h) {
  return __uint_as_float(((unsigned int)h) << 16);
}

// insert (e,s) into sorted top-3 (c0<=c1<=c2); strict < keeps incumbent on ties
__device__ __forceinline__ void ins3(float e, int s,
                                     float& c0, float& c1, float& c2,
                                     int& i0, int& i1, int& i2) {
  bool l0 = e < c0, l1 = e < c1, l2 = e < c2;
  float nf0 = fminf(e, c0);
  float nf1 = __builtin_amdgcn_fmed3f(e, c0, c1);
  float nf2 = __builtin_amdgcn_fmed3f(e, c1, c2);
  i2 = l1 ? i1 : (l2 ? s : i2);
  i1 = l0 ? i0 : (l1 ? s : i1);
  i0 = l0 ? s : i0;
  c0 = nf0; c1 = nf1; c2 = nf2;
}

// ---------- prep: weights fp32->bf16 + pack xyz2 (one launch) ----------
__global__ __launch_bounds__(256) void k_prep(const float* __restrict__ W0,
                                              const float* __restrict__ W1,
                                              const float* __restrict__ xyz2,
                                              ushort_t* __restrict__ W0b,
                                              ushort_t* __restrict__ W1b,
                                              float4* __restrict__ x2p) {
  int i = blockIdx.x * 256 + threadIdx.x;  // grid 576
  if (i < 98304) {
    W0b[i] = f2bf(W0[i]);
  } else if (i < 131072) {
    W1b[i - 98304] = f2bf(W1[i - 98304]);
  } else {
    int idx = i - 131072;  // 16384
    int b = idx >> 11, s = idx & (S_ - 1);
    const float* base = xyz2 + (size_t)b * 3 * S_;
    float x = base[s], y = base[S_ + s], z = base[2 * S_ + s];
    x2p[idx] = make_float4(x, y, z, 0.5f * (x * x + y * y + z * z));
  }
}

// ---------- transpose points2 [B,256,S] -> p2t bf16 [B,S,256] ----------
__global__ void k_tr_p2(const float* __restrict__ P2, ushort_t* __restrict__ p2t) {
  __shared__ float t[32][33];
  int b = blockIdx.z;
  int s0 = blockIdx.x * 32;
  int c0 = blockIdx.y * 32;
  int tx = threadIdx.x, ty = threadIdx.y;  // (32,8)
#pragma unroll
  for (int j = 0; j < 4; j++) {
    int c = c0 + ty + j * 8;
    t[ty + j * 8][tx] = P2[((size_t)b * D2_ + c) * S_ + s0 + tx];
  }
  __syncthreads();
#pragma unroll
  for (int j = 0; j < 4; j++) {
    int s = s0 + ty + j * 8;
    p2t[((size_t)b * S_ + s) * D2_ + c0 + tx] = f2bf(t[tx][ty + j * 8]);
  }
}

// ---------- transpose points1 [B,128,N] -> Xc cols 0..127 (bf16, row stride 384) ----------
__global__ void k_tr_p1(const float* __restrict__ P1, ushort_t* __restrict__ Xc) {
  __shared__ float t[32][33];
  int b = blockIdx.z;
  int n0 = blockIdx.x * 32;
  int c0 = blockIdx.y * 32;
  int tx = threadIdx.x, ty = threadIdx.y;
#pragma unroll
  for (int j = 0; j < 4; j++) {
    int c = c0 + ty + j * 8;
    t[ty + j * 8][tx] = P1[((size_t)b * D1_ + c) * N_ + n0 + tx];
  }
  __syncthreads();
#pragma unroll
  for (int j = 0; j < 4; j++) {
    int n = n0 + ty + j * 8;
    Xc[((size_t)b * N_ + n) * INCH_ + c0 + tx] = f2bf(t[tx][ty + j * 8]);
  }
}

// ---------- kNN + interpolate: 512 blocks x 256 threads, 128 queries/block ----------
// Each lane owns ONE query over half of S (waves paired: wv&1 = S-half).
// Survey points streamed via the SCALAR pipe (wave-uniform s_load) — zero
// VALU/LDS cost per point. Pass1 tracks top-3 VALUES only (min+2*med3);
// pass2 re-streams, collects candidates e<=c2 behind an __any wave-skip.
__global__ __launch_bounds__(256) void k_knn(const float* __restrict__ xyz1,
                                             const float4* __restrict__ x2p,
                                             const ushort_t* __restrict__ p2t,
                                             ushort_t* __restrict__ Xc) {
  __shared__ float pv[2][128][3];
  __shared__ float cvv[2][128][3];
  __shared__ int   cii[2][128][3];
  __shared__ float wsh[128 * 3];
  __shared__ int   ish[128 * 3];
  const int t = threadIdx.x;
  const int q0 = blockIdx.x * 128;
  const int b = q0 >> 13;
  const int lane = t & 63;
  const int wv = __builtin_amdgcn_readfirstlane(t >> 6);  // 0..3, forced uniform
  const int half = wv & 1;
  const int qL = (wv >> 1) * 64 + lane;  // 0..127
  const int n = (q0 & (N_ - 1)) + qL;
  const float qx = xyz1[((size_t)b * 3 + 0) * N_ + n];
  const float qy = xyz1[((size_t)b * 3 + 1) * N_ + n];
  const float qz = xyz1[((size_t)b * 3 + 2) * N_ + n];
  const float4* __restrict__ xp = x2p + (size_t)b * S_ + half * 1024;

  // ---- pass 1: top-3 values only ----
  float c0 = 3e38f, c1 = 3e38f, c2 = 3e38f;
#pragma unroll 8
  for (int g = 0; g < 1024; ++g) {
    float4 P = xp[g];  // wave-uniform -> s_load
    float e = fmaf(-qx, P.x, fmaf(-qy, P.y, fmaf(-qz, P.z, P.w)));
    float n1 = __builtin_amdgcn_fmed3f(e, c0, c1);
    float n2 = __builtin_amdgcn_fmed3f(e, c1, c2);
    c0 = fminf(e, c0); c1 = n1; c2 = n2;
  }
  pv[half][qL][0] = c0; pv[half][qL][1] = c1; pv[half][qL][2] = c2;
  __syncthreads();
#pragma unroll
  for (int k = 0; k < 3; ++k) {
    float e = pv[1 - half][qL][k];
    float n1 = __builtin_amdgcn_fmed3f(e, c0, c1);
    float n2 = __builtin_amdgcn_fmed3f(e, c1, c2);
    c0 = fminf(e, c0); c1 = n1; c2 = n2;
  }
  // c2 is now the true global 3rd-smallest value for this query

  // ---- pass 2: candidate collection (increasing s within half -> exact ties) ----
  float v0 = 3e38f, v1 = 3e38f, v2 = 3e38f;
  int i0 = 0x7fffffff, i1 = 0x7fffffff, i2 = 0x7fffffff;
  const int sb = half * 1024;
#pragma unroll 4
  for (int g = 0; g < 1024; ++g) {
    float4 P = xp[g];
    float e = fmaf(-qx, P.x, fmaf(-qy, P.y, fmaf(-qz, P.z, P.w)));
    if (__any(e <= c2)) {
      if (e <= c2) ins3(e, sb + g, v0, v1, v2, i0, i1, i2);
    }
  }
  cvv[half][qL][0] = v0; cvv[half][qL][1] = v1; cvv[half][qL][2] = v2;
  cii[half][qL][0] = i0; cii[half][qL][1] = i1; cii[half][qL][2] = i2;
  __syncthreads();
  if (half == 0) {
    // merge: lower half incumbent, insert upper half (ascending) -> exact order
    float m0 = cvv[0][qL][0], m1 = cvv[0][qL][1], m2 = cvv[0][qL][2];
    int j0 = cii[0][qL][0], j1 = cii[0][qL][1], j2 = cii[0][qL][2];
#pragma unroll
    for (int k = 0; k < 3; ++k)
      ins3(cvv[1][qL][k], cii[1][qL][k], m0, m1, m2, j0, j1, j2);
    float nrm1 = qx * qx + qy * qy + qz * qz;
    float dd0 = fmaf(2.f, m0, nrm1);
    float dd1 = fmaf(2.f, m1, nrm1);
    float dd2 = fmaf(2.f, m2, nrm1);
    float r0 = 1.f / (dd0 + 1e-8f);
    float r1 = 1.f / (dd1 + 1e-8f);
    float r2 = 1.f / (dd2 + 1e-8f);
    float rs = 1.f / (r0 + r1 + r2);
    wsh[qL * 3 + 0] = r0 * rs; wsh[qL * 3 + 1] = r1 * rs; wsh[qL * 3 + 2] = r2 * rs;
    ish[qL * 3 + 0] = j0; ish[qL * 3 + 1] = j1; ish[qL * 3 + 2] = j2;
  }
  __syncthreads();
  // ---- gather: 4 queries in parallel (4 waves), 64 lanes x 4 channels ----
  int grp = t >> 6;
  size_t sbase2 = (size_t)b * S_;
#pragma unroll 2
  for (int it = 0; it < 32; ++it) {
    int ql = it * 4 + grp;
    int q = q0 + ql;
    float w0 = wsh[ql * 3 + 0], w1 = wsh[ql * 3 + 1], w2 = wsh[ql * 3 + 2];
    int j0 = ish[ql * 3 + 0], j1 = ish[ql * 3 + 1], j2 = ish[ql * 3 + 2];
    ushort4 a0 = *(const ushort4*)&p2t[(sbase2 + j0) * D2_ + lane * 4];
    ushort4 a1 = *(const ushort4*)&p2t[(sbase2 + j1) * D2_ + lane * 4];
    ushort4 a2 = *(const ushort4*)&p2t[(sbase2 + j2) * D2_ + lane * 4];
    ushort4 o;
    o.x = f2bf(w0 * bf2f(a0.x) + w1 * bf2f(a1.x) + w2 * bf2f(a2.x));
    o.y = f2bf(w0 * bf2f(a0.y) + w1 * bf2f(a1.y) + w2 * bf2f(a2.y));
    o.z = f2bf(w0 * bf2f(a0.z) + w1 * bf2f(a1.z) + w2 * bf2f(a2.z));
    o.w = f2bf(w0 * bf2f(a0.w) + w1 * bf2f(a1.w) + w2 * bf2f(a2.w));
    *(ushort4*)&Xc[(size_t)q * INCH_ + D1_ + lane * 4] = o;
  }
}

// ---------- GEMM1: Y1b[M,256](bf16) = Xc[M,384] * W0b[256,384]^T, 128x256 tile ----------
__global__ __launch_bounds__(512) void k_gemm1(const ushort_t* __restrict__ A,
                                               const ushort_t* __restrict__ Bw,
                                               ushort_t* __restrict__ Cc,
                                               float* __restrict__ sum,
                                               float* __restrict__ ssq) {
  __shared__ __align__(16) ushort_t As[128 * 32];
  __shared__ __align__(16) ushort_t Bs[256 * 32];
  const int tid = threadIdx.x;
  const int m0 = blockIdx.x * 128;
  const int wave = tid >> 6;
  const int lane = tid & 63;
  const int quad = lane >> 4;
  const int l16 = lane & 15;
  const int wrow = (wave >> 2) * 64;   // 2 row-waves
  const int wcol = (wave & 3) * 64;    // 4 col-waves
  floatx4 acc[4][4];
#pragma unroll
  for (int i = 0; i < 4; i++)
#pragma unroll
    for (int j = 0; j < 4; j++) acc[i][j] = (floatx4){0.f, 0.f, 0.f, 0.f};

  for (int k0 = 0; k0 < INCH_; k0 += 32) {
    {
      int row = tid >> 2, seg = tid & 3;
      *(uint4*)&As[row * 32 + seg * 8] = *(const uint4*)&A[(size_t)(m0 + row) * INCH_ + k0 + seg * 8];
    }
#pragma unroll
    for (int it = 0; it < 2; it++) {
      int l = tid + it * 512;
      int row = l >> 2, seg = l & 3;
      *(uint4*)&Bs[row * 32 + seg * 8] = *(const uint4*)&Bw[(size_t)row * INCH_ + k0 + seg * 8];
    }
    __syncthreads();
    bf16x8 af[4], bfr[4];
#pragma unroll
    for (int mt = 0; mt < 4; mt++) af[mt] = *(const bf16x8*)&As[(wrow + mt * 16 + l16) * 32 + quad * 8];
#pragma unroll
    for (int nt = 0; nt < 4; nt++) bfr[nt] = *(const bf16x8*)&Bs[(wcol + nt * 16 + l16) * 32 + quad * 8];
#pragma unroll
    for (int mt = 0; mt < 4; mt++)
#pragma unroll
      for (int nt = 0; nt < 4; nt++)
        acc[mt][nt] = __builtin_amdgcn_mfma_f32_16x16x32_bf16(af[mt], bfr[nt], acc[mt][nt], 0, 0, 0);
    __syncthreads();
  }
#pragma unroll
  for (int mt = 0; mt < 4; mt++) {
#pragma unroll
    for (int i = 0; i < 4; i++) {
      int row = m0 + wrow + mt * 16 + quad * 4 + i;
#pragma unroll
      for (int nt = 0; nt < 4; nt++) {
        int col = wcol + nt * 16 + l16;
        Cc[(size_t)row * 256 + col] = f2bf(acc[mt][nt][i]);
      }
    }
  }
  // fused BN stats (f32 acc)
#pragma unroll
  for (int nt = 0; nt < 4; nt++) {
    float s = 0.f, s2 = 0.f;
#pragma unroll
    for (int mt = 0; mt < 4; mt++)
#pragma unroll
      for (int i = 0; i < 4; i++) {
        float v = acc[mt][nt][i];
        s += v;
        s2 = fmaf(v, v, s2);
      }
    s += __shfl_xor(s, 16);  s2 += __shfl_xor(s2, 16);
    s += __shfl_xor(s, 32);  s2 += __shfl_xor(s2, 32);
    if (quad == 0) {
      int col = wcol + nt * 16 + l16;
      atomicAdd(&sum[col], s);
      atomicAdd(&ssq[col], s2);
    }
  }
}

// ---------- GEMM2: Y2b[M,128](bf16) = relu(BN0(Y1b))[M,256] * W1b[128,256]^T ----------
// BN0 scale/shift computed in-kernel from sum0/ssq0 (finalize folded in).
__global__ __launch_bounds__(256) void k_gemm2(const ushort_t* __restrict__ Y1,
                                               const ushort_t* __restrict__ Bw,
                                               const float* __restrict__ sum0,
                                               const float* __restrict__ ssq0,
                                               const float* __restrict__ g0,
                                               const float* __restrict__ be0,
                                               ushort_t* __restrict__ Cc,
                                               float* __restrict__ sum,
                                               float* __restrict__ ssq) {
  __shared__ __align__(16) ushort_t As[128 * 32];
  __shared__ __align__(16) ushort_t Bs[128 * 32];
  __shared__ float scs[256], shs[256];
  const int tid = threadIdx.x;
  const int m0 = blockIdx.x * 128;
  const int wave = tid >> 6;
  const int lane = tid & 63;
  const int quad = lane >> 4;
  const int l16 = lane & 15;
  const int wrow = (wave >> 1) * 64;
  const int wcol = (wave & 1) * 64;
  {
    float mean = sum0[tid] * (1.f / 65536.f);
    float var = ssq0[tid] * (1.f / 65536.f) - mean * mean;
    float sc = rsqrtf(var + 1e-5f) * g0[tid];
    scs[tid] = sc;
    shs[tid] = be0[tid] - mean * sc;
  }
  floatx4 acc[4][4];
#pragma unroll
  for (int i = 0; i < 4; i++)
#pragma unroll
    for (int j = 0; j < 4; j++) acc[i][j] = (floatx4){0.f, 0.f, 0.f, 0.f};
  __syncthreads();

  for (int k0 = 0; k0 < 256; k0 += 32) {
#pragma unroll
    for (int it = 0; it < 2; it++) {
      int l = tid + it * 256;
      int row = l >> 2, seg = l & 3;
      ushort4 y01 = *(const ushort4*)&Y1[(size_t)(m0 + row) * 256 + k0 + seg * 8];
      ushort4 y23 = *(const ushort4*)&Y1[(size_t)(m0 + row) * 256 + k0 + seg * 8 + 4];
      int c = k0 + seg * 8;
      ushort4 o0, o1;
      o0.x = f2bf(fmaxf(fmaf(bf2f(y01.x), scs[c + 0], shs[c + 0]), 0.f));
      o0.y = f2bf(fmaxf(fmaf(bf2f(y01.y), scs[c + 1], shs[c + 1]), 0.f));
      o0.z = f2bf(fmaxf(fmaf(bf2f(y01.z), scs[c + 2], shs[c + 2]), 0.f));
      o0.w = f2bf(fmaxf(fmaf(bf2f(y01.w), scs[c + 3], shs[c + 3]), 0.f));
      o1.x = f2bf(fmaxf(fmaf(bf2f(y23.x), scs[c + 4], shs[c + 4]), 0.f));
      o1.y = f2bf(fmaxf(fmaf(bf2f(y23.y), scs[c + 5], shs[c + 5]), 0.f));
      o1.z = f2bf(fmaxf(fmaf(bf2f(y23.z), scs[c + 6], shs[c + 6]), 0.f));
      o1.w = f2bf(fmaxf(fmaf(bf2f(y23.w), scs[c + 7], shs[c + 7]), 0.f));
      *(ushort4*)&As[row * 32 + seg * 8] = o0;
      *(ushort4*)&As[row * 32 + seg * 8 + 4] = o1;
    }
#pragma unroll
    for (int it = 0; it < 2; it++) {
      int l = tid + it * 256;
      int row = l >> 2, seg = l & 3;
      *(uint4*)&Bs[row * 32 + seg * 8] = *(const uint4*)&Bw[(size_t)row * 256 + k0 + seg * 8];
    }
    __syncthreads();
    bf16x8 af[4], bfr[4];
#pragma unroll
    for (int mt = 0; mt < 4; mt++) af[mt] = *(const bf16x8*)&As[(wrow + mt * 16 + l16) * 32 + quad * 8];
#pragma unroll
    for (int nt = 0; nt < 4; nt++) bfr[nt] = *(const bf16x8*)&Bs[(wcol + nt * 16 + l16) * 32 + quad * 8];
#pragma unroll
    for (int mt = 0; mt < 4; mt++)
#pragma unroll
      for (int nt = 0; nt < 4; nt++)
        acc[mt][nt] = __builtin_amdgcn_mfma_f32_16x16x32_bf16(af[mt], bfr[nt], acc[mt][nt], 0, 0, 0);
    __syncthreads();
  }
#pragma unroll
  for (int mt = 0; mt < 4; mt++) {
#pragma unroll
    for (int i = 0; i < 4; i++) {
      int row = m0 + wrow + mt * 16 + quad * 4 + i;
#pragma unroll
      for (int nt = 0; nt < 4; nt++) {
        int col = wcol + nt * 16 + l16;
        Cc[(size_t)row * 128 + col] = f2bf(acc[mt][nt][i]);
      }
    }
  }
#pragma unroll
  for (int nt = 0; nt < 4; nt++) {
    float s = 0.f, s2 = 0.f;
#pragma unroll
    for (int mt = 0; mt < 4; mt++)
#pragma unroll
      for (int i = 0; i < 4; i++) {
        float v = acc[mt][nt][i];
        s += v;
        s2 = fmaf(v, v, s2);
      }
    s += __shfl_xor(s, 16);  s2 += __shfl_xor(s2, 16);
    s += __shfl_xor(s, 32);  s2 += __shfl_xor(s2, 32);
    if (quad == 0) {
      int col = wcol + nt * 16 + l16;
      atomicAdd(&sum[col], s);
      atomicAdd(&ssq[col], s2);
    }
  }
}

// ---------- final: BN1 (folded finalize) + relu + transpose to [B,128,N] ----------
__global__ __launch_bounds__(256) void k_out(const ushort_t* __restrict__ Y2,
                                             const float* __restrict__ sum1,
                                             const float* __restrict__ ssq1,
                                             const float* __restrict__ g1,
                                             const float* __restrict__ be1,
                                             float* __restrict__ out) {
  __shared__ float t[64 * 129];
  __shared__ float sc1[128], sh1[128];
  int tid = threadIdx.x;
  int p0 = blockIdx.x * 64;  // 1024 blocks
  int b = p0 >> 13;
  int n0 = p0 & (N_ - 1);
  if (tid < 128) {
    float mean = sum1[tid] * (1.f / 65536.f);
    float var = ssq1[tid] * (1.f / 65536.f) - mean * mean;
    float sc = rsqrtf(var + 1e-5f) * g1[tid];
    sc1[tid] = sc;
    sh1[tid] = be1[tid] - mean * sc;
  }
#pragma unroll
  for (int it = 0; it < 8; it++) {
    int idx = it * 256 + tid;        // [0,2048)
    int r = idx >> 5, c4 = (idx & 31) * 4;
    ushort4 v = *(const ushort4*)&Y2[(size_t)(p0 + r) * 128 + c4];
    t[r * 129 + c4 + 0] = bf2f(v.x);
    t[r * 129 + c4 + 1] = bf2f(v.y);
    t[r * 129 + c4 + 2] = bf2f(v.z);
    t[r * 129 + c4 + 3] = bf2f(v.w);
  }
  __syncthreads();
#pragma unroll
  for (int it = 0; it < 32; it++) {
    int idx = it * 256 + tid;
    int j = idx & 63, c = idx >> 6;
    float v = fmaxf(fmaf(t[j * 129 + c], sc1[c], sh1[c]), 0.f);
    out[((size_t)(b * 128 + c)) * N_ + n0 + j] = v;
  }
}

extern "C" void kernel_launch(void* const* d_in, const int* in_sizes, int n_in,
                              void* d_out, int out_size, void* d_ws, size_t ws_size,
                              hipStream_t stream) {
  const float* xyz1    = (const float*)d_in[0];
  const float* xyz2    = (const float*)d_in[1];
  const float* points1 = (const float*)d_in[2];
  const float* points2 = (const float*)d_in[3];
  const float* W0 = (const float*)d_in[4];
  const float* g0 = (const float*)d_in[6];
  const float* be0 = (const float*)d_in[7];
  const float* W1 = (const float*)d_in[8];
  const float* g1 = (const float*)d_in[10];
  const float* be1 = (const float*)d_in[11];
  float* out = (float*)d_out;
  char* ws = (char*)d_ws;

  float* sum0   = (float*)(ws + OFF_STATS);
  float* ssq0   = sum0 + 256;
  float* sum1   = sum0 + 512;
  float* ssq1   = sum0 + 640;
  ushort_t* W0b = (ushort_t*)(ws + OFF_W0B);
  ushort_t* W1b = (ushort_t*)(ws + OFF_W1B);
  float4* x2p   = (float4*)(ws + OFF_X2P);
  ushort_t* p2t = (ushort_t*)(ws + OFF_P2T);
  ushort_t* Xc  = (ushort_t*)(ws + OFF_XC);
  ushort_t* Y1b = (ushort_t*)(ws + OFF_Y1);
  ushort_t* Y2b = (ushort_t*)(ws + OFF_XC);  // overlays Xc (dead after GEMM1)

  hipMemsetAsync(ws + OFF_STATS, 0, 6144, stream);
  k_prep<<<576, 256, 0, stream>>>(W0, W1, xyz2, W0b, W1b, x2p);
  k_tr_p2<<<dim3(64, 8, 8), dim3(32, 8), 0, stream>>>(points2, p2t);
  k_tr_p1<<<dim3(256, 4, 8), dim3(32, 8), 0, stream>>>(points1, Xc);
  k_knn<<<512, 256, 0, stream>>>(xyz1, x2p, p2t, Xc);
  k_gemm1<<<512, 512, 0, stream>>>(Xc, W0b, Y1b, sum0, ssq0);
  k_gemm2<<<512, 256, 0, stream>>>(Y1b, W1b, sum0, ssq0, g0, be0, Y2b, sum1, ssq1);
  k_out<<<1024, 256, 0, stream>>>(Y2b, sum1, ssq1, g1, be1, out);
}

// Round 8
// 277.778 us; speedup vs baseline: 1.2630x; 1.2630x over previous
//
#include <hip/hip_runtime.h>

typedef unsigned short ushort_t;
typedef __bf16 bf16x8 __attribute__((ext_vector_type(8)));
typedef float floatx4 __attribute__((ext_vector_type(4)));

#define B_ 8
#define N_ 8192
#define S_ 2048
#define D1_ 128
#define D2_ 256
#define INCH_ 384
#define M_ 65536  // B*N

// async global->LDS, 16B per lane; LDS dest = wave-uniform base + lane*16
#define ASYNC_CP16(g, l)                                                  \
  __builtin_amdgcn_global_load_lds(                                       \
      (const __attribute__((address_space(1))) void*)(g),                 \
      (__attribute__((address_space(3))) void*)(l), 16, 0, 0)

// ---------- workspace layout (bytes) ----------
constexpr size_t OFF_STATS = 0;          // 6144 B used
constexpr size_t OFF_W0B   = 8192;       // 256*384*2 = 196608
constexpr size_t OFF_W1B   = 204800;     // 128*256*2 = 65536
constexpr size_t OFF_X2P   = 270336;     // 8*2048*16 = 262144 (float4 x,y,z,0.5*|x|^2)
constexpr size_t OFF_P2T   = 532480;     // 8*2048*256*2 = 8388608 bf16
constexpr size_t OFF_XC    = 8921088;    // 65536*384*2 = 50331648 bf16 ; Y2b overlays after GEMM1
constexpr size_t OFF_Y1    = 59252736;   // 65536*256*2 = 33554432 bf16

__device__ __forceinline__ ushort_t f2bf(float f) {
  unsigned int u = __float_as_uint(f);
  unsigned int r = u + 0x7fffu + ((u >> 16) & 1u);
  return (ushort_t)(r >> 16);
}
__device__ __forceinline__ float bf2f(ushort_t h) {
  return __uint_as_float(((unsigned int)h) << 16);
}

// insert (e,s) into sorted top-3 (c0<=c1<=c2); strict < keeps incumbent on ties
__device__ __forceinline__ void ins3(float e, int s,
                                     float& c0, float& c1, float& c2,
                                     int& i0, int& i1, int& i2) {
  bool l0 = e < c0, l1 = e < c1, l2 = e < c2;
  float nf0 = fminf(e, c0);
  float nf1 = __builtin_amdgcn_fmed3f(e, c0, c1);
  float nf2 = __builtin_amdgcn_fmed3f(e, c1, c2);
  i2 = l1 ? i1 : (l2 ? s : i2);
  i1 = l0 ? i0 : (l1 ? s : i1);
  i0 = l0 ? s : i0;
  c0 = nf0; c1 = nf1; c2 = nf2;
}

// ---------- prep: weights fp32->bf16 + pack xyz2 (one launch) ----------
__global__ __launch_bounds__(256) void k_prep(const float* __restrict__ W0,
                                              const float* __restrict__ W1,
                                              const float* __restrict__ xyz2,
                                              ushort_t* __restrict__ W0b,
                                              ushort_t* __restrict__ W1b,
                                              float4* __restrict__ x2p) {
  int i = blockIdx.x * 256 + threadIdx.x;  // grid 576
  if (i < 98304) {
    W0b[i] = f2bf(W0[i]);
  } else if (i < 131072) {
    W1b[i - 98304] = f2bf(W1[i - 98304]);
  } else {
    int idx = i - 131072;  // 16384
    int b = idx >> 11, s = idx & (S_ - 1);
    const float* base = xyz2 + (size_t)b * 3 * S_;
    float x = base[s], y = base[S_ + s], z = base[2 * S_ + s];
    x2p[idx] = make_float4(x, y, z, 0.5f * (x * x + y * y + z * z));
  }
}

// ---------- transpose points2 [B,256,S] -> p2t bf16 [B,S,256] ----------
__global__ void k_tr_p2(const float* __restrict__ P2, ushort_t* __restrict__ p2t) {
  __shared__ float t[32][33];
  int b = blockIdx.z;
  int s0 = blockIdx.x * 32;
  int c0 = blockIdx.y * 32;
  int tx = threadIdx.x, ty = threadIdx.y;  // (32,8)
#pragma unroll
  for (int j = 0; j < 4; j++) {
    int c = c0 + ty + j * 8;
    t[ty + j * 8][tx] = P2[((size_t)b * D2_ + c) * S_ + s0 + tx];
  }
  __syncthreads();
#pragma unroll
  for (int j = 0; j < 4; j++) {
    int s = s0 + ty + j * 8;
    p2t[((size_t)b * S_ + s) * D2_ + c0 + tx] = f2bf(t[tx][ty + j * 8]);
  }
}

// ---------- transpose points1 [B,128,N] -> Xc cols 0..127 (bf16, row stride 384) ----------
__global__ void k_tr_p1(const float* __restrict__ P1, ushort_t* __restrict__ Xc) {
  __shared__ float t[32][33];
  int b = blockIdx.z;
  int n0 = blockIdx.x * 32;
  int c0 = blockIdx.y * 32;
  int tx = threadIdx.x, ty = threadIdx.y;
#pragma unroll
  for (int j = 0; j < 4; j++) {
    int c = c0 + ty + j * 8;
    t[ty + j * 8][tx] = P1[((size_t)b * D1_ + c) * N_ + n0 + tx];
  }
  __syncthreads();
#pragma unroll
  for (int j = 0; j < 4; j++) {
    int n = n0 + ty + j * 8;
    Xc[((size_t)b * N_ + n) * INCH_ + c0 + tx] = f2bf(t[tx][ty + j * 8]);
  }
}

// ---------- kNN + interpolate: 1024 blocks x 512 threads, 64 queries/block ----------
// r5 design (measured 78 us, VALUBusy ~100%): sub = t&7 owns a 256-pt S-chunk,
// qg = t>>3 one query; 8 sub-lists of a query live in one wave -> shfl merge.
__global__ __launch_bounds__(512, 8) void k_knn(const float* __restrict__ xyz1,
                                                const float4* __restrict__ x2p,
                                                const ushort_t* __restrict__ p2t,
                                                ushort_t* __restrict__ Xc) {
  __shared__ float4 xs[S_];          // 32 KB
  __shared__ float wsh[64 * 3];
  __shared__ int   ish[64 * 3];
  int t = threadIdx.x;
  int q0 = blockIdx.x * 64;
  int b = q0 >> 13;
  int n0 = q0 & (N_ - 1);
  for (int l = t; l < S_; l += 512) xs[l] = x2p[(size_t)b * S_ + l];
  int sub = t & 7;
  int qg = t >> 3;  // [0,64)
  int n = n0 + qg;
  float qx = xyz1[((size_t)b * 3 + 0) * N_ + n];
  float qy = xyz1[((size_t)b * 3 + 1) * N_ + n];
  float qz = xyz1[((size_t)b * 3 + 2) * N_ + n];
  float c0 = 3e38f, c1 = 3e38f, c2 = 3e38f;
  int i0 = 0, i1 = 0, i2 = 0;
  __syncthreads();
  // e = 0.5*|x2|^2 - dot(x1,x2); true dist d = 2e + |x1|^2 (monotone in e)
  int sbase = sub << 8;
  int stag = (sub * 33) & 255;  // stagger: 8 sub-addresses hit disjoint bank groups
  int s = sbase + stag;
  float4 P = xs[s];
#pragma unroll 4
  for (int i = 0; i < 256; ++i) {
    int ii = (i + 1 + stag) & 255;
    int sn = sbase + ii;
    float4 Pn = xs[sn];  // prefetch next point
    float e = fmaf(-qx, P.x, fmaf(-qy, P.y, fmaf(-qz, P.z, P.w)));
    ins3(e, s, c0, c1, c2, i0, i1, i2);
    P = Pn; s = sn;
  }
  // merge the 8 sub-lists within the wave (lanes differ only in low-3 bits)
#pragma unroll
  for (int d = 1; d < 8; d <<= 1) {
    float e0 = __shfl_xor(c0, d); int s0 = __shfl_xor(i0, d);
    float e1 = __shfl_xor(c1, d); int s1 = __shfl_xor(i1, d);
    float e2 = __shfl_xor(c2, d); int s2 = __shfl_xor(i2, d);
    ins3(e0, s0, c0, c1, c2, i0, i1, i2);
    ins3(e1, s1, c0, c1, c2, i0, i1, i2);
    ins3(e2, s2, c0, c1, c2, i0, i1, i2);
  }
  if (sub == 0) {
    float nrm1 = qx * qx + qy * qy + qz * qz;
    float dd0 = fmaf(2.f, c0, nrm1);
    float dd1 = fmaf(2.f, c1, nrm1);
    float dd2 = fmaf(2.f, c2, nrm1);
    float r0 = 1.f / (dd0 + 1e-8f);
    float r1 = 1.f / (dd1 + 1e-8f);
    float r2 = 1.f / (dd2 + 1e-8f);
    float rs = 1.f / (r0 + r1 + r2);
    wsh[qg * 3 + 0] = r0 * rs; wsh[qg * 3 + 1] = r1 * rs; wsh[qg * 3 + 2] = r2 * rs;
    ish[qg * 3 + 0] = i0; ish[qg * 3 + 1] = i1; ish[qg * 3 + 2] = i2;
  }
  __syncthreads();
  // gather: 8 queries in parallel (8 waves), 64 lanes x 4 channels each
  int lane = t & 63, grp = t >> 6;
  size_t sbase2 = (size_t)b * S_;
#pragma unroll 2
  for (int it = 0; it < 8; ++it) {
    int ql = it * 8 + grp;
    int q = q0 + ql;
    float w0 = wsh[ql * 3 + 0], w1 = wsh[ql * 3 + 1], w2 = wsh[ql * 3 + 2];
    int j0 = ish[ql * 3 + 0], j1 = ish[ql * 3 + 1], j2 = ish[ql * 3 + 2];
    ushort4 a0 = *(const ushort4*)&p2t[(sbase2 + j0) * D2_ + lane * 4];
    ushort4 a1 = *(const ushort4*)&p2t[(sbase2 + j1) * D2_ + lane * 4];
    ushort4 a2 = *(const ushort4*)&p2t[(sbase2 + j2) * D2_ + lane * 4];
    ushort4 o;
    o.x = f2bf(w0 * bf2f(a0.x) + w1 * bf2f(a1.x) + w2 * bf2f(a2.x));
    o.y = f2bf(w0 * bf2f(a0.y) + w1 * bf2f(a1.y) + w2 * bf2f(a2.y));
    o.z = f2bf(w0 * bf2f(a0.z) + w1 * bf2f(a1.z) + w2 * bf2f(a2.z));
    o.w = f2bf(w0 * bf2f(a0.w) + w1 * bf2f(a1.w) + w2 * bf2f(a2.w));
    *(ushort4*)&Xc[(size_t)q * INCH_ + D1_ + lane * 4] = o;
  }
}

// ---------- GEMM1: Y1b[M,256](bf16) = Xc[M,384] * W0b[256,384]^T, 128x256 tile ----------
// Async global->LDS (width 16) staging for both A and B tiles.
__global__ __launch_bounds__(512) void k_gemm1(const ushort_t* __restrict__ A,
                                               const ushort_t* __restrict__ Bw,
                                               ushort_t* __restrict__ Cc,
                                               float* __restrict__ sum,
                                               float* __restrict__ ssq) {
  __shared__ __align__(16) ushort_t As[128 * 32];
  __shared__ __align__(16) ushort_t Bs[256 * 32];
  const int tid = threadIdx.x;
  const int m0 = blockIdx.x * 128;
  const int wave = tid >> 6;
  const int wuni = __builtin_amdgcn_readfirstlane(wave);  // 0..7
  const int lane = tid & 63;
  const int quad = lane >> 4;
  const int l16 = lane & 15;
  const int wrow = (wave >> 2) * 64;   // 2 row-waves
  const int wcol = (wave & 3) * 64;    // 4 col-waves
  const int arow = tid >> 2, aseg = tid & 3;
  floatx4 acc[4][4];
#pragma unroll
  for (int i = 0; i < 4; i++)
#pragma unroll
    for (int j = 0; j < 4; j++) acc[i][j] = (floatx4){0.f, 0.f, 0.f, 0.f};

  for (int k0 = 0; k0 < INCH_; k0 += 32) {
    // A tile: 128x32 bf16 = 512 lanes x 16B ; dest byte = tid*16
    ASYNC_CP16(&A[(size_t)(m0 + arow) * INCH_ + k0 + aseg * 8], &As[wuni * 512]);
    // B tile: 256x32 bf16 = 1024 lane-loads (2 its)
#pragma unroll
    for (int it = 0; it < 2; it++) {
      int l = tid + it * 512;
      int row = l >> 2, seg = l & 3;
      ASYNC_CP16(&Bw[(size_t)row * INCH_ + k0 + seg * 8], &Bs[it * 4096 + wuni * 512]);
    }
    __syncthreads();
    bf16x8 af[4], bfr[4];
#pragma unroll
    for (int mt = 0; mt < 4; mt++) af[mt] = *(const bf16x8*)&As[(wrow + mt * 16 + l16) * 32 + quad * 8];
#pragma unroll
    for (int nt = 0; nt < 4; nt++) bfr[nt] = *(const bf16x8*)&Bs[(wcol + nt * 16 + l16) * 32 + quad * 8];
#pragma unroll
    for (int mt = 0; mt < 4; mt++)
#pragma unroll
      for (int nt = 0; nt < 4; nt++)
        acc[mt][nt] = __builtin_amdgcn_mfma_f32_16x16x32_bf16(af[mt], bfr[nt], acc[mt][nt], 0, 0, 0);
    __syncthreads();
  }
#pragma unroll
  for (int mt = 0; mt < 4; mt++) {
#pragma unroll
    for (int i = 0; i < 4; i++) {
      int row = m0 + wrow + mt * 16 + quad * 4 + i;
#pragma unroll
      for (int nt = 0; nt < 4; nt++) {
        int col = wcol + nt * 16 + l16;
        Cc[(size_t)row * 256 + col] = f2bf(acc[mt][nt][i]);
      }
    }
  }
  // fused BN stats (f32 acc)
#pragma unroll
  for (int nt = 0; nt < 4; nt++) {
    float s = 0.f, s2 = 0.f;
#pragma unroll
    for (int mt = 0; mt < 4; mt++)
#pragma unroll
      for (int i = 0; i < 4; i++) {
        float v = acc[mt][nt][i];
        s += v;
        s2 = fmaf(v, v, s2);
      }
    s += __shfl_xor(s, 16);  s2 += __shfl_xor(s2, 16);
    s += __shfl_xor(s, 32);  s2 += __shfl_xor(s2, 32);
    if (quad == 0) {
      int col = wcol + nt * 16 + l16;
      atomicAdd(&sum[col], s);
      atomicAdd(&ssq[col], s2);
    }
  }
}

// ---------- GEMM2: Y2b[M,128](bf16) = relu(BN0(Y1b))[M,256] * W1b[128,256]^T ----------
// BN0 scale/shift computed in-kernel (finalize folded). B staged async.
__global__ __launch_bounds__(256) void k_gemm2(const ushort_t* __restrict__ Y1,
                                               const ushort_t* __restrict__ Bw,
                                               const float* __restrict__ sum0,
                                               const float* __restrict__ ssq0,
                                               const float* __restrict__ g0,
                                               const float* __restrict__ be0,
                                               ushort_t* __restrict__ Cc,
                                               float* __restrict__ sum,
                                               float* __restrict__ ssq) {
  __shared__ __align__(16) ushort_t As[128 * 32];
  __shared__ __align__(16) ushort_t Bs[128 * 32];
  __shared__ float scs[256], shs[256];
  const int tid = threadIdx.x;
  const int m0 = blockIdx.x * 128;
  const int wave = tid >> 6;
  const int wuni = __builtin_amdgcn_readfirstlane(wave);  // 0..3
  const int lane = tid & 63;
  const int quad = lane >> 4;
  const int l16 = lane & 15;
  const int wrow = (wave >> 1) * 64;
  const int wcol = (wave & 1) * 64;
  {
    float mean = sum0[tid] * (1.f / 65536.f);
    float var = ssq0[tid] * (1.f / 65536.f) - mean * mean;
    float sc = rsqrtf(var + 1e-5f) * g0[tid];
    scs[tid] = sc;
    shs[tid] = be0[tid] - mean * sc;
  }
  floatx4 acc[4][4];
#pragma unroll
  for (int i = 0; i < 4; i++)
#pragma unroll
    for (int j = 0; j < 4; j++) acc[i][j] = (floatx4){0.f, 0.f, 0.f, 0.f};
  __syncthreads();

  for (int k0 = 0; k0 < 256; k0 += 32) {
    // B tile async: 128x32 = 512 lane-loads (2 its); dest byte = (tid+it*256)*16
#pragma unroll
    for (int it = 0; it < 2; it++) {
      int l = tid + it * 256;
      int row = l >> 2, seg = l & 3;
      ASYNC_CP16(&Bw[(size_t)row * 256 + k0 + seg * 8], &Bs[it * 2048 + wuni * 512]);
    }
    // A tile: BN0+relu transform on the fly (VGPR path)
#pragma unroll
    for (int it = 0; it < 2; it++) {
      int l = tid + it * 256;
      int row = l >> 2, seg = l & 3;
      ushort4 y01 = *(const ushort4*)&Y1[(size_t)(m0 + row) * 256 + k0 + seg * 8];
      ushort4 y23 = *(const ushort4*)&Y1[(size_t)(m0 + row) * 256 + k0 + seg * 8 + 4];
      int c = k0 + seg * 8;
      ushort4 o0, o1;
      o0.x = f2bf(fmaxf(fmaf(bf2f(y01.x), scs[c + 0], shs[c + 0]), 0.f));
      o0.y = f2bf(fmaxf(fmaf(bf2f(y01.y), scs[c + 1], shs[c + 1]), 0.f));
      o0.z = f2bf(fmaxf(fmaf(bf2f(y01.z), scs[c + 2], shs[c + 2]), 0.f));
      o0.w = f2bf(fmaxf(fmaf(bf2f(y01.w), scs[c + 3], shs[c + 3]), 0.f));
      o1.x = f2bf(fmaxf(fmaf(bf2f(y23.x), scs[c + 4], shs[c + 4]), 0.f));
      o1.y = f2bf(fmaxf(fmaf(bf2f(y23.y), scs[c + 5], shs[c + 5]), 0.f));
      o1.z = f2bf(fmaxf(fmaf(bf2f(y23.z), scs[c + 6], shs[c + 6]), 0.f));
      o1.w = f2bf(fmaxf(fmaf(bf2f(y23.w), scs[c + 7], shs[c + 7]), 0.f));
      *(ushort4*)&As[row * 32 + seg * 8] = o0;
      *(ushort4*)&As[row * 32 + seg * 8 + 4] = o1;
    }
    __syncthreads();
    bf16x8 af[4], bfr[4];
#pragma unroll
    for (int mt = 0; mt < 4; mt++) af[mt] = *(const bf16x8*)&As[(wrow + mt * 16 + l16) * 32 + quad * 8];
#pragma unroll
    for (int nt = 0; nt < 4; nt++) bfr[nt] = *(const bf16x8*)&Bs[(wcol + nt * 16 + l16) * 32 + quad * 8];
#pragma unroll
    for (int mt = 0; mt < 4; mt++)
#pragma unroll
      for (int nt = 0; nt < 4; nt++)
        acc[mt][nt] = __builtin_amdgcn_mfma_f32_16x16x32_bf16(af[mt], bfr[nt], acc[mt][nt], 0, 0, 0);
    __syncthreads();
  }
#pragma unroll
  for (int mt = 0; mt < 4; mt++) {
#pragma unroll
    for (int i = 0; i < 4; i++) {
      int row = m0 + wrow + mt * 16 + quad * 4 + i;
#pragma unroll
      for (int nt = 0; nt < 4; nt++) {
        int col = wcol + nt * 16 + l16;
        Cc[(size_t)row * 128 + col] = f2bf(acc[mt][nt][i]);
      }
    }
  }
#pragma unroll
  for (int nt = 0; nt < 4; nt++) {
    float s = 0.f, s2 = 0.f;
#pragma unroll
    for (int mt = 0; mt < 4; mt++)
#pragma unroll
      for (int i = 0; i < 4; i++) {
        float v = acc[mt][nt][i];
        s += v;
        s2 = fmaf(v, v, s2);
      }
    s += __shfl_xor(s, 16);  s2 += __shfl_xor(s2, 16);
    s += __shfl_xor(s, 32);  s2 += __shfl_xor(s2, 32);
    if (quad == 0) {
      int col = wcol + nt * 16 + l16;
      atomicAdd(&sum[col], s);
      atomicAdd(&ssq[col], s2);
    }
  }
}

// ---------- final: BN1 (folded finalize) + relu + transpose to [B,128,N] ----------
__global__ __launch_bounds__(256) void k_out(const ushort_t* __restrict__ Y2,
                                             const float* __restrict__ sum1,
                                             const float* __restrict__ ssq1,
                                             const float* __restrict__ g1,
                                             const float* __restrict__ be1,
                                             float* __restrict__ out) {
  __shared__ float t[64 * 129];
  __shared__ float sc1[128], sh1[128];
  int tid = threadIdx.x;
  int p0 = blockIdx.x * 64;  // 1024 blocks
  int b = p0 >> 13;
  int n0 = p0 & (N_ - 1);
  if (tid < 128) {
    float mean = sum1[tid] * (1.f / 65536.f);
    float var = ssq1[tid] * (1.f / 65536.f) - mean * mean;
    float sc = rsqrtf(var + 1e-5f) * g1[tid];
    sc1[tid] = sc;
    sh1[tid] = be1[tid] - mean * sc;
  }
#pragma unroll
  for (int it = 0; it < 8; it++) {
    int idx = it * 256 + tid;        // [0,2048)
    int r = idx >> 5, c4 = (idx & 31) * 4;
    ushort4 v = *(const ushort4*)&Y2[(size_t)(p0 + r) * 128 + c4];
    t[r * 129 + c4 + 0] = bf2f(v.x);
    t[r * 129 + c4 + 1] = bf2f(v.y);
    t[r * 129 + c4 + 2] = bf2f(v.z);
    t[r * 129 + c4 + 3] = bf2f(v.w);
  }
  __syncthreads();
#pragma unroll
  for (int it = 0; it < 32; it++) {
    int idx = it * 256 + tid;
    int j = idx & 63, c = idx >> 6;
    float v = fmaxf(fmaf(t[j * 129 + c], sc1[c], sh1[c]), 0.f);
    out[((size_t)(b * 128 + c)) * N_ + n0 + j] = v;
  }
}

extern "C" void kernel_launch(void* const* d_in, const int* in_sizes, int n_in,
                              void* d_out, int out_size, void* d_ws, size_t ws_size,
                              hipStream_t stream) {
  const float* xyz1    = (const float*)d_in[0];
  const float* xyz2    = (const float*)d_in[1];
  const float* points1 = (const float*)d_in[2];
  const float* points2 = (const float*)d_in[3];
  const float* W0 = (const float*)d_in[4];
  const float* g0 = (const float*)d_in[6];
  const float* be0 = (const float*)d_in[7];
  const float* W1 = (const float*)d_in[8];
  const float* g1 = (const float*)d_in[10];
  const float* be1 = (const float*)d_in[11];
  float* out = (float*)d_out;
  char* ws = (char*)d_ws;

  float* sum0   = (float*)(ws + OFF_STATS);
  float* ssq0   = sum0 + 256;
  float* sum1   = sum0 + 512;
  float* ssq1   = sum0 + 640;
  ushort_t* W0b = (ushort_t*)(ws + OFF_W0B);
  ushort_t* W1b = (ushort_t*)(ws + OFF_W1B);
  float4* x2p   = (float4*)(ws + OFF_X2P);
  ushort_t* p2t = (ushort_t*)(ws + OFF_P2T);
  ushort_t* Xc  = (ushort_t*)(ws + OFF_XC);
  ushort_t* Y1b = (ushort_t*)(ws + OFF_Y1);
  ushort_t* Y2b = (ushort_t*)(ws + OFF_XC);  // overlays Xc (dead after GEMM1)

  hipMemsetAsync(ws + OFF_STATS, 0, 6144, stream);
  k_prep<<<576, 256, 0, stream>>>(W0, W1, xyz2, W0b, W1b, x2p);
  k_tr_p2<<<dim3(64, 8, 8), dim3(32, 8), 0, stream>>>(points2, p2t);
  k_tr_p1<<<dim3(256, 4, 8), dim3(32, 8), 0, stream>>>(points1, Xc);
  k_knn<<<1024, 512, 0, stream>>>(xyz1, x2p, p2t, Xc);
  k_gemm1<<<512, 512, 0, stream>>>(Xc, W0b, Y1b, sum0, ssq0);
  k_gemm2<<<512, 256, 0, stream>>>(Y1b, W1b, sum0, ssq0, g0, be0, Y2b, sum1, ssq1);
  k_out<<<1024, 256, 0, stream>>>(Y2b, sum1, ssq1, g1, be1, out);
}